// Round 15
// baseline (143.648 us; speedup 1.0000x reference)
//
#include <hip/hip_runtime.h>

// Per-sample depthwise 7x7 cross-correlation, NHWC, SAME padding.
// inputs:  [B,H,W,C] fp32, kernels: [B,7,7,C] fp32, out: [B,H,W,C] fp32.
// out[b,y,x,c] = sum_{i,j} in[b, y+i-3, x+j-3, c] * ker[b,i,j,c]  (zero pad)
//
// R15 = R14 (fp16 dot2, 512-thr blocks, rebased tap immediates, alignbit
// odd-pairs, dynamic ring, 64-VGPR tier) + WEIGHT HOIST: packed weight quads
// for kernel rows 0..4 live in PINNED registers (+20 VGPRs, 40->~60, still
// inside the 64 tier); only rows 5,6 are re-read from LDS per pass. Cuts the
// loop-invariant LDS re-read traffic 7->2 b128/pass (~42->12us of LDS pipe)
// and shortens each pass's lgkm-wait chain. The asm memory clobber stays to
// stop LICM of the remaining 2 quads (hoisting them too would hit 68 regs).

#define BB 32
#define HH 128
#define WW 128
#define CC 128
#define KH 7
#define KW 7

#define XPT 4                        // x outputs per thread
#define NTAP (XPT + KW - 1)          // 10 tap columns per thread
#define XG 4                         // x-groups per block (512 threads / 128 c)
#define SLABW (XG * XPT)             // 16 output columns per block
#define NXS (WW / SLABW)             // 8 x-slabs
#define YSPLIT 4
#define YROWS (HH / YSPLIT)          // 32 output rows per block
#define GRID (BB * NXS * YSPLIT)     // 1024 blocks = 4 per CU
#define WSLOTS 28                    // per-c packed-weight uints (7 rows x 4 pairs)
#define NPASS (YROWS + KH - 1)       // 38 single-row passes

typedef _Float16 half2_t __attribute__((ext_vector_type(2)));

static __device__ __forceinline__ half2_t pk(float a, float b) {
#if __has_builtin(__builtin_amdgcn_cvt_pkrtz)
    return __builtin_bit_cast(half2_t, __builtin_amdgcn_cvt_pkrtz(a, b));
#else
    half2_t r; r.x = (_Float16)a; r.y = (_Float16)b; return r;
#endif
}

static __device__ __forceinline__ float dot2f(unsigned w, half2_t t, float c) {
#if __has_builtin(__builtin_amdgcn_fdot2)
    return __builtin_amdgcn_fdot2(__builtin_bit_cast(half2_t, w), t, c, false);
#else
    half2_t wv = __builtin_bit_cast(half2_t, w);
    return fmaf((float)wv.x, (float)t.x, fmaf((float)wv.y, (float)t.y, c));
#endif
}

__global__ __launch_bounds__(512) void crossconv_kernel(
    const float* __restrict__ in,
    const float* __restrict__ ker,
    float* __restrict__ out)
{
    __shared__ unsigned lds_w[CC * WSLOTS];   // 14336 B

    const int tid = threadIdx.x;
    const int c  = tid & (CC - 1);   // lanes contiguous in c -> coalesced
    const int xg = __builtin_amdgcn_readfirstlane(tid >> 7);   // 0..3, wave-uniform

    // Bijective XCD swizzle (GRID=1024, 128 blocks/XCD = 4 whole samples).
    const int bid = blockIdx.x;
    const int swz = (bid & 7) * (GRID / 8) + (bid >> 3);
    const int b  = swz >> 5;         // 32 blocks per sample (8 xs x 4 yh)
    const int xs = (swz >> 2) & 7;
    const int yh = swz & 3;
    const int x0 = xs * SLABW + xg * XPT;  // wave-uniform (scalar)
    const int y0 = yh * YROWS;

    // Stage packed weights into LDS: slot s (0..27) -> row i=s>>2, pair q=s&3.
    // q<3: (w[i][2q], w[i][2q+1]); q==3: (w[i][6], 0).
    {
        const float* kb = ker + ((size_t)b * KH * KW) * CC + c;
        for (int s = xg; s < WSLOTS; s += XG) {
            const int i = s >> 2, q = s & 3;
            half2_t pr;
            if (q < 3) {
                const int f0 = i * KW + 2 * q;
                pr = pk(kb[f0 * CC], kb[(f0 + 1) * CC]);
            } else {
                pr = pk(kb[(i * KW + 6) * CC], 0.0f);
            }
            lds_w[c * WSLOTS + s] = __builtin_bit_cast(unsigned, pr);
        }
    }
    __syncthreads();

    const float* ib = in  + ((size_t)b * HH * WW) * CC;
    float*       ob = out + ((size_t)b * HH * WW) * CC;
    const unsigned* wlds = &lds_w[c * WSLOTS];

    // Hoist kernel rows 0..4 into pinned registers (20 VGPRs). The asm pin
    // makes them opaque values: no remat, no LICM interaction. Rows 5,6 stay
    // in LDS and are re-read per pass (clobber below prevents their LICM).
    uint4 wr[5];
    #pragma unroll
    for (int i = 0; i < 5; ++i) {
        wr[i] = *(const uint4*)(wlds + i * 4);
        asm("" : "+v"(wr[i].x), "+v"(wr[i].y), "+v"(wr[i].z), "+v"(wr[i].w));
    }

    const bool interior = (x0 >= 3) && (x0 + XPT + 2 < WW);

    // Tap loads rebased to column x0-1: per-tap offsets (j-2)*512 B fall in
    // [-1024, 3584] -> 13-bit immediates, one 64-bit base add per pass.
    auto load_taps = [&](float* t, int yi) {
        if (yi < 0 || yi >= HH) {
            #pragma unroll
            for (int j = 0; j < NTAP; ++j) t[j] = 0.0f;
            return;
        }
        const float* base = ib + (size_t)yi * WW * CC + (x0 - 1) * CC + c;
        if (interior) {
            #pragma unroll
            for (int j = 0; j < NTAP; ++j)
                t[j] = base[(j - 2) * CC];                 // imm offsets
        } else {
            #pragma unroll
            for (int j = 0; j < NTAP; ++j) {
                const int xx = x0 - 3 + j;
                t[j] = (xx >= 0 && xx < WW) ? base[(j - 2) * CC] : 0.0f;
            }
        }
    };

    // Sliding ring: acc[s][xo] partial for output row y = yi-3+s.
    float acc[KH][XPT];
    #pragma unroll
    for (int s = 0; s < KH; ++s)
        #pragma unroll
        for (int xo = 0; xo < XPT; ++xo) acc[s][xo] = 0.0f;

    const int yi0 = y0 - 3;

    // Packed taps: e[k]=(t[2k],t[2k+1]) k=0..4; o[k] from e via alignbit;
    // o[4]=(t9,0). Even xo: e[xo/2+q]; odd xo: o[(xo-1)/2+q].
    float t[NTAP];
    half2_t e[5], o[5];
    load_taps(t, yi0);
    #pragma unroll
    for (int k = 0; k < 5; ++k) e[k] = pk(t[2 * k], t[2 * k + 1]);
    #pragma unroll
    for (int k = 0; k < 4; ++k)
        o[k] = __builtin_bit_cast(half2_t, __builtin_amdgcn_alignbit(
                   __builtin_bit_cast(unsigned, e[k + 1]),
                   __builtin_bit_cast(unsigned, e[k]), 16));
    o[4] = pk(t[9], 0.0f);

    #pragma unroll 1
    for (int p = 0; p < NPASS; ++p) {
        const int yi = yi0 + p;

        // Issue next row's tap loads; the dot pass hides the latency.
        load_taps(t, (p + 1 < NPASS) ? (yi + 1) : HH);

        // Prevent LICM of the 2 LDS-resident quads (hoisting them would push
        // past the 64-VGPR tier and spill).
        asm volatile("" ::: "memory");

        #pragma unroll
        for (int i = 0; i < KH; ++i) {
            const uint4 wq = (i < 5) ? wr[i] : *(const uint4*)(wlds + i * 4);
            const int s = 6 - i;
            #pragma unroll
            for (int xo = 0; xo < XPT; ++xo) {
                float a = acc[s][xo];
                if ((xo & 1) == 0) {
                    const int k0 = xo >> 1;
                    a = dot2f(wq.x, e[k0],     a);
                    a = dot2f(wq.y, e[k0 + 1], a);
                    a = dot2f(wq.z, e[k0 + 2], a);
                    a = dot2f(wq.w, e[k0 + 3], a);
                } else {
                    const int k0 = (xo - 1) >> 1;
                    a = dot2f(wq.x, o[k0],     a);
                    a = dot2f(wq.y, o[k0 + 1], a);
                    a = dot2f(wq.z, o[k0 + 2], a);
                    a = dot2f(wq.w, o[k0 + 3], a);
                }
                acc[s][xo] = a;
            }
        }

        const int y = yi - 3;
        if (y >= y0) {                       // upper bound guaranteed by loop end
            float* orow = ob + ((size_t)y * WW + x0) * CC + c;
            #pragma unroll
            for (int xo = 0; xo < XPT; ++xo)
                orow[xo * CC] = acc[0][xo];
        }

        // Shift ring, open fresh top slot.
        #pragma unroll
        for (int s = 0; s < KH - 1; ++s)
            #pragma unroll
            for (int xo = 0; xo < XPT; ++xo) acc[s][xo] = acc[s + 1][xo];
        #pragma unroll
        for (int xo = 0; xo < XPT; ++xo) acc[KH - 1][xo] = 0.0f;

        // Pack the prefetched row for the next pass.
        #pragma unroll
        for (int k = 0; k < 5; ++k) e[k] = pk(t[2 * k], t[2 * k + 1]);
        #pragma unroll
        for (int k = 0; k < 4; ++k)
            o[k] = __builtin_bit_cast(half2_t, __builtin_amdgcn_alignbit(
                       __builtin_bit_cast(unsigned, e[k + 1]),
                       __builtin_bit_cast(unsigned, e[k]), 16));
        o[4] = pk(t[9], 0.0f);
    }
}

extern "C" void kernel_launch(void* const* d_in, const int* in_sizes, int n_in,
                              void* d_out, int out_size, void* d_ws, size_t ws_size,
                              hipStream_t stream) {
    const float* in  = (const float*)d_in[0];
    const float* ker = (const float*)d_in[1];
    float*       out = (float*)d_out;

    crossconv_kernel<<<GRID, 512, 0, stream>>>(in, ker, out);
}

// Round 16
// 128.134 us; speedup vs baseline: 1.1211x; 1.1211x over previous
//
#include <hip/hip_runtime.h>

// Per-sample depthwise 7x7 cross-correlation, NHWC, SAME padding.
// inputs:  [B,H,W,C] fp32, kernels: [B,7,7,C] fp32, out: [B,H,W,C] fp32.
// out[b,y,x,c] = sum_{i,j} in[b, y+i-3, x+j-3, c] * ker[b,i,j,c]  (zero pad)
//
// R16: XPT=8 via v_pk_fma_f16 with fp16 ACCUMULATION (lo/hi = adjacent x).
// acc = half2[7][4] (28 regs for 8 outputs). Weights pre-broadcast (w,w) in
// LDS [c][7i][8 slots] (quads 16B-aligned, stride 15 quads -> bijective mod 8,
// conflict-free). Per-output issue: 196 pk_fma + ~80 overhead per 8 outputs
// (~35/out vs R14's ~40.5/out) and HALF the per-pass stall events per output.
// 256-thr blocks, GRID=1024 (4 blocks/CU). 64-VGPR tier by construction; no
// occupancy attributes, no multi-pass unrolling (R2/R6/R9/R13 lessons).

#define BB 32
#define HH 128
#define WW 128
#define CC 128
#define KH 7
#define KW 7

#define XPT 8                        // x outputs per thread (4 half2 pairs)
#define NTAP (XPT + KW - 1)          // 14 tap columns per thread
#define XG 2                         // x-groups per block (256 threads / 128 c)
#define SLABW (XG * XPT)             // 16 output columns per block
#define NXS (WW / SLABW)             // 8 x-slabs
#define YSPLIT 4
#define YROWS (HH / YSPLIT)          // 32 output rows per block
#define GRID (BB * NXS * YSPLIT)     // 1024 blocks = 4 per CU
#define WSTRIDE 60                   // per-c weight uints (7 rows x 8 + pad)
#define NPASS (YROWS + KH - 1)       // 38 single-row passes

typedef _Float16 half2_t __attribute__((ext_vector_type(2)));

static __device__ __forceinline__ half2_t pk(float a, float b) {
#if __has_builtin(__builtin_amdgcn_cvt_pkrtz)
    return __builtin_bit_cast(half2_t, __builtin_amdgcn_cvt_pkrtz(a, b));
#else
    half2_t r; r.x = (_Float16)a; r.y = (_Float16)b; return r;
#endif
}

static __device__ __forceinline__ half2_t bc(unsigned u) {
    return __builtin_bit_cast(half2_t, u);
}

__global__ __launch_bounds__(256) void crossconv_kernel(
    const float* __restrict__ in,
    const float* __restrict__ ker,
    float* __restrict__ out)
{
    __shared__ unsigned lds_w[CC * WSTRIDE];   // 30720 B

    const int tid = threadIdx.x;
    const int c  = tid & (CC - 1);   // lanes contiguous in c -> coalesced
    const int xg = __builtin_amdgcn_readfirstlane(tid >> 7);   // 0..1, wave-uniform

    // Bijective XCD swizzle (GRID=1024, 128 blocks/XCD = 4 whole samples).
    const int bid = blockIdx.x;
    const int swz = (bid & 7) * (GRID / 8) + (bid >> 3);
    const int b  = swz >> 5;         // 32 blocks per sample (8 xs x 4 yh)
    const int xs = (swz >> 2) & 7;
    const int yh = swz & 3;
    const int x0 = xs * SLABW + xg * XPT;  // wave-uniform (scalar)
    const int y0 = yh * YROWS;

    // Stage PRE-BROADCAST weights into LDS: f = i*7+j (0..48) ->
    // lds_w[c*60 + i*8 + j] = (w_f, w_f) packed fp16.
    {
        const float* kb = ker + ((size_t)b * KH * KW) * CC + c;
        for (int f = xg; f < KH * KW; f += XG) {
            const int i = f / KW, j = f - i * KW;
            const float wv = kb[f * CC];
            lds_w[c * WSTRIDE + i * 8 + j] =
                __builtin_bit_cast(unsigned, pk(wv, wv));
        }
    }
    __syncthreads();

    const float* ib = in  + ((size_t)b * HH * WW) * CC;
    float*       ob = out + ((size_t)b * HH * WW) * CC;
    const unsigned* wp = &lds_w[c * WSTRIDE];

    const bool interior = (x0 >= 3) && (x0 + NTAP - 3 < WW);

    // Tap loads rebased to column x0+2: offsets (j-5)*512 B for j=0..12 fall
    // in [-2560, 3584] (13-bit imm); t[13] via a second base.
    auto load_taps = [&](float* t, int yi) {
        if (yi < 0 || yi >= HH) {
            #pragma unroll
            for (int j = 0; j < NTAP; ++j) t[j] = 0.0f;
            return;
        }
        const float* base = ib + (size_t)yi * WW * CC + (x0 + 2) * CC + c;
        if (interior) {
            #pragma unroll
            for (int j = 0; j < 13; ++j)
                t[j] = base[(j - 5) * CC];                 // imm offsets
            t[13] = (base + 8 * CC)[0];
        } else {
            #pragma unroll
            for (int j = 0; j < NTAP; ++j) {
                const int xx = x0 - 3 + j;
                t[j] = (xx >= 0 && xx < WW) ? base[(j - 5) * CC] : 0.0f;
            }
        }
    };

    // Sliding ring: acc[s][q] = half2 partials for outputs (x0+2q, x0+2q+1)
    // of output row y = yi-3+s.
    half2_t acc[KH][XPT / 2];
    #pragma unroll
    for (int s = 0; s < KH; ++s)
        #pragma unroll
        for (int q = 0; q < XPT / 2; ++q) acc[s][q] = half2_t{0, 0};

    const int yi0 = y0 - 3;

    // Packed tap pairs p[m] = (t[m], t[m+1]), m=0..12:
    // even m=2k from cvt_pkrtz; odd m=2k+1 via alignbit(e[k+1], e[k]).
    // Output pair q uses p[2q+j], j=0..6.
    float t[NTAP];
    half2_t p[13];
    auto pack = [&]() {
        #pragma unroll
        for (int k = 0; k < 7; ++k) p[2 * k] = pk(t[2 * k], t[2 * k + 1]);
        #pragma unroll
        for (int k = 0; k < 6; ++k)
            p[2 * k + 1] = __builtin_bit_cast(half2_t, __builtin_amdgcn_alignbit(
                               __builtin_bit_cast(unsigned, p[2 * k + 2]),
                               __builtin_bit_cast(unsigned, p[2 * k]), 16));
    };

    load_taps(t, yi0);
    pack();

    #pragma unroll 1
    for (int pp = 0; pp < NPASS; ++pp) {
        const int yi = yi0 + pp;

        // Issue next row's tap loads; the dot pass hides the latency.
        load_taps(t, (pp + 1 < NPASS) ? (yi + 1) : HH);

        // Keep per-pass LDS weight reads in the loop (hoisting 49 broadcast
        // pairs would blow the 64-VGPR tier and spill).
        asm volatile("" ::: "memory");

        #pragma unroll
        for (int i = 0; i < KH; ++i) {
            const uint4 q0 = *(const uint4*)(wp + i * 8);      // w0..w3 bcast
            const uint4 q1 = *(const uint4*)(wp + i * 8 + 4);  // w4..w6 bcast
            const int s = 6 - i;
            #pragma unroll
            for (int q = 0; q < XPT / 2; ++q) {
                half2_t a = acc[s][q];
                a = bc(q0.x) * p[2 * q + 0] + a;
                a = bc(q0.y) * p[2 * q + 1] + a;
                a = bc(q0.z) * p[2 * q + 2] + a;
                a = bc(q0.w) * p[2 * q + 3] + a;
                a = bc(q1.x) * p[2 * q + 4] + a;
                a = bc(q1.y) * p[2 * q + 5] + a;
                a = bc(q1.z) * p[2 * q + 6] + a;
                acc[s][q] = a;
            }
        }

        const int y = yi - 3;
        if (y >= y0) {                       // upper bound guaranteed by loop end
            float* orow = ob + ((size_t)y * WW + x0) * CC + c;
            #pragma unroll
            for (int q = 0; q < XPT / 2; ++q) {
                orow[(2 * q) * CC]     = (float)acc[0][q].x;
                orow[(2 * q + 1) * CC] = (float)acc[0][q].y;
            }
        }

        // Shift ring, open fresh top slot.
        #pragma unroll
        for (int s = 0; s < KH - 1; ++s)
            #pragma unroll
            for (int q = 0; q < XPT / 2; ++q) acc[s][q] = acc[s + 1][q];
        #pragma unroll
        for (int q = 0; q < XPT / 2; ++q) acc[KH - 1][q] = half2_t{0, 0};

        // Pack the prefetched row for the next pass.
        pack();
    }
}

extern "C" void kernel_launch(void* const* d_in, const int* in_sizes, int n_in,
                              void* d_out, int out_size, void* d_ws, size_t ws_size,
                              hipStream_t stream) {
    const float* in  = (const float*)d_in[0];
    const float* ker = (const float*)d_in[1];
    float*       out = (float*)d_out;

    crossconv_kernel<<<GRID, 256, 0, stream>>>(in, ker, out);
}